// Round 1
// baseline (68.546 us; speedup 1.0000x reference)
//
#include <hip/hip_runtime.h>

#define NUM_CLASSES 80
#define A_NUM 120000
#define B_NUM 8
#define N_BOX 64

// One thread per (batch, anchor). Phase 1: stage 64 GT boxes in LDS.
// Phase 2: per-anchor argmax-IoU over 64 boxes, write reg_target (float4)
// and anchor_state. Phase 3: block-cooperative coalesced write of the
// 80-wide one-hot cls_target rows (20 float4 per anchor).
__global__ __launch_bounds__(256) void compute_targets_kernel(
    const float* __restrict__ annotations,  // (B, 64, 5)
    const float4* __restrict__ anchors4,    // (A, 4)
    float* __restrict__ out)                // cls | reg | states, concat flat
{
#pragma clang fp contract(off)
    __shared__ float4 sbox[N_BOX];
    __shared__ int    slab[N_BOX];
    __shared__ int    scls[256];  // per-local-anchor: class idx if positive else -1

    const int tid = threadIdx.x;
    const int b   = blockIdx.y;
    const int a0  = blockIdx.x * 256;
    const int a   = a0 + tid;

    if (tid < N_BOX) {
        const float* ann = annotations + ((size_t)b * N_BOX + tid) * 5;
        const float x0 = ann[0], y0 = ann[1], x1 = ann[2], y1 = ann[3];
        sbox[tid] = make_float4(x0, y0, x1, y1);
        slab[tid] = (int)ann[4];
    }
    __syncthreads();

    int clsidx = -1;
    if (a < A_NUM) {
        const float4 anc = anchors4[a];
        const float wa = anc.z - anc.x;
        const float ha = anc.w - anc.y;
        const float area_a = wa * ha;

        float best_iou = -1.0f;
        int   best_j   = 0;
#pragma unroll 8
        for (int j = 0; j < N_BOX; ++j) {
            const float4 bx = sbox[j];                       // ds_read_b128 broadcast
            const float area_b = (bx.z - bx.x) * (bx.w - bx.y);
            const float ltx = fmaxf(anc.x, bx.x);
            const float lty = fmaxf(anc.y, bx.y);
            const float rbx = fminf(anc.z, bx.z);
            const float rby = fminf(anc.w, bx.w);
            const float w = fmaxf(rbx - ltx, 0.0f);
            const float h = fmaxf(rby - lty, 0.0f);
            const float inter = w * h;
            const float uni   = (area_a + area_b) - inter;   // contract(off): no fma
            const float iou   = inter / fmaxf(uni, 1e-8f);   // IEEE div, matches np
            if (iou > best_iou) { best_iou = iou; best_j = j; }  // first-max wins
        }

        const bool positive = best_iou >= 0.5f;
        const bool ignore   = (best_iou > 0.4f) && !positive;
        const float state   = positive ? 1.0f : (ignore ? -1.0f : 0.0f);

        const float4 gt = sbox[best_j];
        float4 reg;
        reg.x = ((gt.x - anc.x) / wa) / 0.2f;
        reg.y = ((gt.y - anc.y) / ha) / 0.2f;
        reg.z = ((gt.z - anc.z) / wa) / 0.2f;
        reg.w = ((gt.w - anc.w) / ha) / 0.2f;

        const size_t CLS = (size_t)B_NUM * A_NUM * NUM_CLASSES;
        const size_t REG = (size_t)B_NUM * A_NUM * 4;
        float4* regout = (float4*)(out + CLS);
        regout[(size_t)b * A_NUM + a] = reg;
        out[CLS + REG + (size_t)b * A_NUM + a] = state;

        clsidx = positive ? slab[best_j] : -1;
    }
    scls[tid] = clsidx;
    __syncthreads();

    // cls_target: 256 anchors x 80 floats = 5120 float4, coalesced.
    float4* clsout = (float4*)out + ((size_t)b * A_NUM + a0) * 20;
#pragma unroll
    for (int i = 0; i < 20; ++i) {
        const int pos = i * 256 + tid;
        const int al  = pos / 20;          // local anchor index
        const int q   = pos - al * 20;     // which float4 within the 80-row
        if (a0 + al < A_NUM) {
            const int lab = scls[al];
            const int c0  = q * 4;
            float4 v;
            v.x = (lab == c0    ) ? 1.0f : 0.0f;
            v.y = (lab == c0 + 1) ? 1.0f : 0.0f;
            v.z = (lab == c0 + 2) ? 1.0f : 0.0f;
            v.w = (lab == c0 + 3) ? 1.0f : 0.0f;
            clsout[pos] = v;
        }
    }
}

extern "C" void kernel_launch(void* const* d_in, const int* in_sizes, int n_in,
                              void* d_out, int out_size, void* d_ws, size_t ws_size,
                              hipStream_t stream) {
    const float*  annotations = (const float*)d_in[0];   // (8, 64, 5)
    const float4* anchors     = (const float4*)d_in[1];  // (120000, 4)
    float* out = (float*)d_out;

    dim3 grid((A_NUM + 255) / 256, B_NUM);
    compute_targets_kernel<<<grid, 256, 0, stream>>>(annotations, anchors, out);
}

// Round 2
// 60.669 us; speedup vs baseline: 1.1298x; 1.1298x over previous
//
#include <hip/hip_runtime.h>

#define NUM_CLASSES 80
#define A_NUM 120000
#define B_NUM 8
#define N_BOX 64

typedef float f4 __attribute__((ext_vector_type(4)));

// One thread per (batch, anchor). Phase 1: wave0 stages 64 GT boxes (+areas,
// labels) in LDS; one barrier. Phase 2: per-anchor argmax-IoU over 64 boxes
// (IEEE divides, contract off => bit-matches numpy), nontemporal store of
// reg_target (float4) + anchor_state. Phase 3: WAVE-LOCAL transpose via LDS
// (A_NUM % 64 == 0, so each wave's 64 anchors are self-contained -> no second
// __syncthreads; compiler's lgkmcnt wait orders the same-wave LDS RAW), then
// coalesced nontemporal float4 stores of the 80-wide one-hot rows.
__global__ __launch_bounds__(256, 4) void compute_targets_kernel(
    const float* __restrict__ annotations,  // (B, 64, 5)
    const float4* __restrict__ anchors4,    // (A, 4)
    float* __restrict__ out)                // cls | reg | states, concat flat
{
#pragma clang fp contract(off)
    __shared__ float4 sbox[N_BOX];
    __shared__ float  sarea[N_BOX];
    __shared__ int    slab[N_BOX];
    __shared__ int    scls[256];

    const int tid  = threadIdx.x;
    const int wv   = tid >> 6;
    const int lane = tid & 63;
    const int b    = blockIdx.y;
    const int a0   = blockIdx.x * 256;
    const int aw0  = a0 + wv * 64;   // wave's anchor base
    const int a    = a0 + tid;

    if (tid < N_BOX) {
        const float* ann = annotations + ((size_t)b * N_BOX + tid) * 5;
        const float x0 = ann[0], y0 = ann[1], x1 = ann[2], y1 = ann[3];
        sbox[tid]  = make_float4(x0, y0, x1, y1);
        sarea[tid] = (x1 - x0) * (y1 - y0);   // same f32 ops as reference
        slab[tid]  = (int)ann[4];
    }
    __syncthreads();

    // A_NUM % 64 == 0: a wave is entirely valid or entirely past the end.
    if (aw0 >= A_NUM) return;

    const float4 anc = anchors4[a];
    const float wa = anc.z - anc.x;
    const float ha = anc.w - anc.y;
    const float area_a = wa * ha;

    float best_iou = -1.0f;
    int   best_j   = 0;
#pragma unroll 8
    for (int j = 0; j < N_BOX; ++j) {
        const float4 bx = sbox[j];                    // LDS broadcast
        const float ltx = fmaxf(anc.x, bx.x);
        const float lty = fmaxf(anc.y, bx.y);
        const float rbx = fminf(anc.z, bx.z);
        const float rby = fminf(anc.w, bx.w);
        const float w = fmaxf(rbx - ltx, 0.0f);
        const float h = fmaxf(rby - lty, 0.0f);
        const float inter = w * h;
        const float uni   = (area_a + sarea[j]) - inter;  // contract(off): no fma
        // union >= max(area) >= 1 (wh in [1,257]) so fmax(uni,1e-8) == uni: drop it.
        const float iou   = inter / uni;                  // IEEE div, matches np
        if (iou > best_iou) { best_iou = iou; best_j = j; }  // first-max wins
    }

    const bool positive = best_iou >= 0.5f;
    const bool ignore   = (best_iou > 0.4f) && !positive;
    const float state   = positive ? 1.0f : (ignore ? -1.0f : 0.0f);

    const float4 gt = sbox[best_j];
    f4 reg;
    reg.x = ((gt.x - anc.x) / wa) / 0.2f;
    reg.y = ((gt.y - anc.y) / ha) / 0.2f;
    reg.z = ((gt.z - anc.z) / wa) / 0.2f;
    reg.w = ((gt.w - anc.w) / ha) / 0.2f;

    const size_t CLS = (size_t)B_NUM * A_NUM * NUM_CLASSES;
    const size_t REG = (size_t)B_NUM * A_NUM * 4;
    f4* regout = (f4*)(out + CLS);
    __builtin_nontemporal_store(reg, &regout[(size_t)b * A_NUM + a]);
    __builtin_nontemporal_store(state, &out[CLS + REG + (size_t)b * A_NUM + a]);

    scls[tid] = positive ? slab[best_j] : -1;
    // No barrier: reads below touch only this wave's 64-slot segment.

    // cls_target: this wave's 64 anchors x 80 floats = 1280 float4, coalesced.
    f4* clsout = (f4*)out + ((size_t)b * A_NUM + aw0) * 20;
#pragma unroll
    for (int i = 0; i < 20; ++i) {
        const int pos = i * 64 + lane;
        const int al  = pos / 20;          // local anchor within wave [0,64)
        const int q   = pos - al * 20;     // which float4 within the 80-row
        const int lab = scls[wv * 64 + al];
        const int c0  = q * 4;
        f4 v;
        v.x = (lab == c0    ) ? 1.0f : 0.0f;
        v.y = (lab == c0 + 1) ? 1.0f : 0.0f;
        v.z = (lab == c0 + 2) ? 1.0f : 0.0f;
        v.w = (lab == c0 + 3) ? 1.0f : 0.0f;
        __builtin_nontemporal_store(v, &clsout[pos]);
    }
}

extern "C" void kernel_launch(void* const* d_in, const int* in_sizes, int n_in,
                              void* d_out, int out_size, void* d_ws, size_t ws_size,
                              hipStream_t stream) {
    const float*  annotations = (const float*)d_in[0];   // (8, 64, 5)
    const float4* anchors     = (const float4*)d_in[1];  // (120000, 4)
    float* out = (float*)d_out;

    dim3 grid((A_NUM + 255) / 256, B_NUM);
    compute_targets_kernel<<<grid, 256, 0, stream>>>(annotations, anchors, out);
}